// Round 5
// baseline (246.775 us; speedup 1.0000x reference)
//
#include <hip/hip_runtime.h>

#define TOKENS  16384
#define KDIM    2048
#define NEXP    64
#define TOPK    6
// W pre-split layout: [chunk 32][level 3][kc 2][n 64][40 halfwords]
// chunk = 64 k; kc = 32-k sub-block; n-stride 40 hw (80 B) -> 2-way banks, 16B-aligned
#define NCHUNK  32
#define CH_HW   15360      // halfwords per chunk (30720 B)
#define LV_HW   5120       // halfwords per level within chunk
#define KC_HW   2560       // halfwords per 32-k sub-block (64 n x 40)
#define PW_BYTES (NCHUNK * CH_HW * 2)   // 983040 B in ws

typedef __attribute__((ext_vector_type(8))) short short8;
typedef __attribute__((ext_vector_type(4))) float f32x4;

__device__ __forceinline__ unsigned short bf16rn(float f, float* back) {
  unsigned u = __builtin_bit_cast(unsigned, f);
  unsigned short h = (unsigned short)((u + 0x7FFFu + ((u >> 16) & 1u)) >> 16);
  *back = __builtin_bit_cast(float, (unsigned)h << 16);
  return h;
}

#define GLD16(gp, lp)                                                   \
  __builtin_amdgcn_global_load_lds(                                     \
      (const __attribute__((address_space(1))) unsigned int*)(gp),      \
      (__attribute__((address_space(3))) unsigned int*)(lp), 16, 0, 0)

// Kernel 0: split W[2048][64] fp32 into 3 bf16 limbs, transposed+padded for
// direct LDS staging. One thread per element; 131072 threads.
__global__ __launch_bounds__(256)
void split_w(const float* __restrict__ wg, unsigned short* __restrict__ pw) {
  const int t = blockIdx.x * 256 + threadIdx.x;
  const int n = t & 63, k = t >> 6;
  float w = wg[(size_t)k * NEXP + n];
  float b0, b1, b2;
  unsigned short h = bf16rn(w, &b0);
  float r1 = w - b0;
  unsigned short m = bf16rn(r1, &b1);
  float r2 = r1 - b1;
  unsigned short l = bf16rn(r2, &b2);
  const int base = (k >> 6) * CH_HW + ((k >> 5) & 1) * KC_HW + n * 40 + (k & 31);
  pw[base]            = h;
  pw[base + LV_HW]    = m;
  pw[base + 2*LV_HW]  = l;
}

// Kernel 1: fused GEMM (3-limb bf16 MFMA) + softmax + top-6.
// 256 blocks x 256 threads; block = 64 tokens, wave = 16 tokens x 64 experts.
// Per 32-k step per wave: 2 dwordx4 A-loads, limb split, 12 ds_read_b128,
// 24 MFMA (6 limb-products x 4 N-tiles). W double-buffered via global_load_lds.
__global__ __launch_bounds__(256)
void gemm_topk(const float* __restrict__ x, const unsigned short* __restrict__ pw,
               float* __restrict__ out) {
  __shared__ __align__(16) unsigned short wbuf[2 * CH_HW];   // 61440 B

  const int t    = threadIdx.x;
  const int wave = t >> 6;
  const int lane = t & 63;
  const int q    = lane >> 4;   // quad
  const int c    = lane & 15;
  const size_t m_glob = (size_t)blockIdx.x * 64 + wave * 16 + c;  // A row (m = lane&15)

  f32x4 acc[4];
#pragma unroll
  for (int nt = 0; nt < 4; ++nt) acc[nt] = (f32x4){0.f, 0.f, 0.f, 0.f};

  const char* pwb = (const char*)pw;

  // stage chunk 0
  {
    const char* src = pwb;
#pragma unroll
    for (int sl = wave; sl < 30; sl += 4)
      GLD16(src + sl * 1024 + lane * 16, wbuf + sl * 512);
  }
  __syncthreads();

  const float* ap_base = x + m_glob * KDIM + q * 8;

  for (int ch = 0; ch < NCHUNK; ++ch) {
    const unsigned short* wb = wbuf + (ch & 1) * CH_HW;

    if (ch + 1 < NCHUNK) {   // stage next chunk into other buffer (overlaps compute)
      const char* src = pwb + (size_t)(ch + 1) * CH_HW * 2;
      unsigned short* dst = wbuf + ((ch + 1) & 1) * CH_HW;
#pragma unroll
      for (int sl = wave; sl < 30; sl += 4)
        GLD16(src + sl * 1024 + lane * 16, dst + sl * 512);
    }

    // A loads for both 32-k steps of this chunk
    const float* ap = ap_base + ch * 64;
    float4 pa[2][2];
#pragma unroll
    for (int s = 0; s < 2; ++s) {
      pa[s][0] = *(const float4*)(ap + s * 32);
      pa[s][1] = *(const float4*)(ap + s * 32 + 4);
    }

#pragma unroll
    for (int s = 0; s < 2; ++s) {
      const float xv[8] = {pa[s][0].x, pa[s][0].y, pa[s][0].z, pa[s][0].w,
                           pa[s][1].x, pa[s][1].y, pa[s][1].z, pa[s][1].w};
      short8 Ah, Am, Al;
#pragma unroll
      for (int j = 0; j < 8; ++j) {
        float b0, b1, b2;
        unsigned short h = bf16rn(xv[j], &b0);
        float r1 = xv[j] - b0;
        unsigned short m = bf16rn(r1, &b1);
        float r2 = r1 - b1;
        unsigned short l = bf16rn(r2, &b2);
        Ah[j] = (short)h; Am[j] = (short)m; Al[j] = (short)l;
      }

      const int bo = s * KC_HW + c * 40 + q * 8;   // + nt*16*40 per N-tile
#pragma unroll
      for (int nt = 0; nt < 4; ++nt) {
        const int o = bo + nt * 640;
        short8 Bh = *(const short8*)(wb + o);
        short8 Bm = *(const short8*)(wb + LV_HW + o);
        short8 Bl = *(const short8*)(wb + 2 * LV_HW + o);
        acc[nt] = __builtin_amdgcn_mfma_f32_16x16x32_bf16(Ah, Bh, acc[nt], 0, 0, 0);
        acc[nt] = __builtin_amdgcn_mfma_f32_16x16x32_bf16(Ah, Bm, acc[nt], 0, 0, 0);
        acc[nt] = __builtin_amdgcn_mfma_f32_16x16x32_bf16(Am, Bh, acc[nt], 0, 0, 0);
        acc[nt] = __builtin_amdgcn_mfma_f32_16x16x32_bf16(Am, Bm, acc[nt], 0, 0, 0);
        acc[nt] = __builtin_amdgcn_mfma_f32_16x16x32_bf16(Ah, Bl, acc[nt], 0, 0, 0);
        acc[nt] = __builtin_amdgcn_mfma_f32_16x16x32_bf16(Al, Bh, acc[nt], 0, 0, 0);
      }
    }
    __syncthreads();   // publishes next chunk (vmcnt drain), guards buffer reuse
  }

  // ---- epilogue: logits -> LDS (overlay wbuf), softmax + top-6 per token ----
  float* lg = (float*)wbuf;            // [64 tokens][stride 68] fp32 = 17408 B
#pragma unroll
  for (int nt = 0; nt < 4; ++nt)
#pragma unroll
    for (int r = 0; r < 4; ++r)
      lg[(wave * 16 + q * 4 + r) * 68 + nt * 16 + c] = acc[nt][r];
  __syncthreads();

  const int sub = c;                    // 16 lanes per token, 4 experts/lane
#pragma unroll 1
  for (int it = 0; it < 4; ++it) {
    const int tl  = wave * 16 + it * 4 + q;
    const int tok = blockIdx.x * 64 + tl;
    const float4 p4 = *(const float4*)(lg + tl * 68 + sub * 4);
    float v[4] = {p4.x, p4.y, p4.z, p4.w};

    float m = fmaxf(fmaxf(v[0], v[1]), fmaxf(v[2], v[3]));
#pragma unroll
    for (int off = 1; off < 16; off <<= 1) m = fmaxf(m, __shfl_xor(m, off));
    float e0 = expf(v[0] - m), e1 = expf(v[1] - m), e2 = expf(v[2] - m), e3 = expf(v[3] - m);
    float sden = e0 + e1 + e2 + e3;
#pragma unroll
    for (int off = 1; off < 16; off <<= 1) sden += __shfl_xor(sden, off);
    v[0] = e0 / sden; v[1] = e1 / sden; v[2] = e2 / sden; v[3] = e3 / sden;

    float resv = 0.f; int resi = 0;
#pragma unroll
    for (int r = 0; r < TOPK; ++r) {
      float bv = v[0]; int bi = sub * 4;
#pragma unroll
      for (int j = 1; j < 4; ++j)
        if (v[j] > bv) { bv = v[j]; bi = sub * 4 + j; }   // strict >: low idx on tie
#pragma unroll
      for (int off = 1; off < 16; off <<= 1) {
        const float ov = __shfl_xor(bv, off);
        const int   oi = __shfl_xor(bi, off);
        if (ov > bv || (ov == bv && oi < bi)) { bv = ov; bi = oi; }
      }
      if (sub == r) { resv = bv; resi = bi; }
      if ((bi >> 2) == sub) v[bi & 3] = -1.f;
    }

    if (sub < TOPK) {
      out[(size_t)tok * TOPK + sub] = (float)resi;
      out[(size_t)TOKENS * TOPK + (size_t)tok * TOPK + sub] = resv;
    }
  }
}

extern "C" void kernel_launch(void* const* d_in, const int* in_sizes, int n_in,
                              void* d_out, int out_size, void* d_ws, size_t ws_size,
                              hipStream_t stream) {
  const float* x  = (const float*)d_in[0];
  const float* wg = (const float*)d_in[1];
  float* out = (float*)d_out;
  unsigned short* pw = (unsigned short*)d_ws;   // 983040 B used

  split_w<<<dim3((KDIM * NEXP) / 256), dim3(256), 0, stream>>>(wg, pw);
  gemm_topk<<<dim3(TOKENS / 64), dim3(256), 0, stream>>>(x, pw, out);
}

// Round 6
// 236.085 us; speedup vs baseline: 1.0453x; 1.0453x over previous
//
#include <hip/hip_runtime.h>

#define TOKENS 16384
#define KDIM   2048
#define NEXP   64
#define TOPK   6
#define WSPLIT 4                 // waves per block = K-split factor
#define SPW    16                // 32-k steps per wave (64 total / 4 waves)

typedef __attribute__((ext_vector_type(8))) short    short8;
typedef __attribute__((ext_vector_type(4))) float    f32x4;
typedef __attribute__((ext_vector_type(4))) unsigned uint4v;

__device__ __forceinline__ unsigned short bf16rn(float f, float* back) {
  unsigned u = __builtin_bit_cast(unsigned, f);
  unsigned short h = (unsigned short)((u + 0x7FFFu + ((u >> 16) & 1u)) >> 16);
  *back = __builtin_bit_cast(float, (unsigned)h << 16);
  return h;
}

// Kernel 0: split W[2048][64] into 3 round-to-nearest bf16 limbs, packed in
// MFMA B-fragment order: pw[s][nt][lv][lane][8 hw]; lane=(q=(k>>3)&3)*16+(n&15).
// A wave's B-load is then one coalesced dwordx4 (1024 B) per (nt,lv).
__global__ __launch_bounds__(256)
void split_w(const float* __restrict__ wg, unsigned short* __restrict__ pw) {
  const int t = blockIdx.x * 256 + threadIdx.x;   // 131072 threads
  const int n = t & 63, k = t >> 6;
  const float w = wg[(size_t)k * NEXP + n];
  float b0, b1, b2;
  const unsigned short h = bf16rn(w, &b0);
  const float r1 = w - b0;
  const unsigned short m = bf16rn(r1, &b1);
  const float r2 = r1 - b1;
  const unsigned short l = bf16rn(r2, &b2);
  const int s = k >> 5, q = (k >> 3) & 3, j = k & 7;
  const int lane = q * 16 + (n & 15), nt = n >> 4;
  const size_t base = ((size_t)(s * 12 + nt * 3) * 64 + lane) * 8 + j;
  pw[base]        = h;   // lv stride = 64 lanes * 8 hw = 512
  pw[base + 512]  = m;
  pw[base + 1024] = l;
}

// Kernel 1: fused 3-limb-bf16 MFMA GEMM + softmax + top-6.
// 1024 blocks x 256 threads; block = 16 tokens, 4 waves split K (512 k each).
// K-loop has NO barriers and NO LDS: B streams coalesced from L2-resident pw,
// A streams from HBM with one-step register prefetch; truncation limb-split.
__global__ __launch_bounds__(256, 4)
void gemm_topk(const float* __restrict__ x, const unsigned short* __restrict__ pw,
               float* __restrict__ out) {
  __shared__ float red[WSPLIT * 4 * 64 * 4];   // [w][nt][lane][4] = 16 KB

  const int t    = threadIdx.x;
  const int wave = t >> 6;
  const int lane = t & 63;
  const int q    = lane >> 4;
  const int c    = lane & 15;

  const size_t m_glob = (size_t)blockIdx.x * 16 + c;          // A row (m = lane&15)
  const float*  ap = x + m_glob * KDIM + wave * (SPW * 32) + q * 8;
  const short8* bp = (const short8*)pw + (size_t)(wave * SPW * 12) * 64 + lane;

  f32x4 acc[4];
#pragma unroll
  for (int nt = 0; nt < 4; ++nt) acc[nt] = (f32x4){0.f, 0.f, 0.f, 0.f};

  uint4v a0 = *(const uint4v*)(ap);
  uint4v a1 = *(const uint4v*)(ap + 4);

#pragma unroll 1
  for (int si = 0; si < SPW; ++si) {
    // prefetch next step's A (decouples ~900-cyc HBM latency from use)
    uint4v n0 = a0, n1 = a1;
    if (si + 1 < SPW) {
      n0 = *(const uint4v*)(ap + (si + 1) * 32);
      n1 = *(const uint4v*)(ap + (si + 1) * 32 + 4);
    }

    // all 12 B-fragments for this step (coalesced 1 KB loads, L2-hot)
    const short8* bps  = bp + si * 768;      // 12*64 short8 per step
    const short8* bps2 = bps + 384;          // nt 2..3 (keep offsets < 8 KB imm)
    short8 B[4][3];
#pragma unroll
    for (int nt = 0; nt < 2; ++nt)
#pragma unroll
      for (int lv = 0; lv < 3; ++lv) {
        B[nt][lv]     = bps[(nt * 3 + lv) * 64];
        B[nt + 2][lv] = bps2[(nt * 3 + lv) * 64];
      }

    // truncation limb-split of A: exact limbs, residual <= 2^-22|a|
    const unsigned u[8] = {a0.x, a0.y, a0.z, a0.w, a1.x, a1.y, a1.z, a1.w};
    unsigned ph[4], pm[4], pl[4];
#pragma unroll
    for (int p = 0; p < 4; ++p) {
      const unsigned ulo = u[2 * p], uhi = u[2 * p + 1];
      ph[p] = (uhi & 0xFFFF0000u) | (ulo >> 16);
      const float flo = __builtin_bit_cast(float, ulo);
      const float fhi = __builtin_bit_cast(float, uhi);
      const float r1lo = flo - __builtin_bit_cast(float, ulo & 0xFFFF0000u);
      const float r1hi = fhi - __builtin_bit_cast(float, uhi & 0xFFFF0000u);
      const unsigned v1lo = __builtin_bit_cast(unsigned, r1lo);
      const unsigned v1hi = __builtin_bit_cast(unsigned, r1hi);
      pm[p] = (v1hi & 0xFFFF0000u) | (v1lo >> 16);
      const float r2lo = r1lo - __builtin_bit_cast(float, v1lo & 0xFFFF0000u);
      const float r2hi = r1hi - __builtin_bit_cast(float, v1hi & 0xFFFF0000u);
      pl[p] = (__builtin_bit_cast(unsigned, r2hi) & 0xFFFF0000u) |
              (__builtin_bit_cast(unsigned, r2lo) >> 16);
    }
    const short8 Ah = __builtin_bit_cast(short8, (uint4v){ph[0], ph[1], ph[2], ph[3]});
    const short8 Am = __builtin_bit_cast(short8, (uint4v){pm[0], pm[1], pm[2], pm[3]});
    const short8 Al = __builtin_bit_cast(short8, (uint4v){pl[0], pl[1], pl[2], pl[3]});

#pragma unroll
    for (int nt = 0; nt < 4; ++nt) {
      acc[nt] = __builtin_amdgcn_mfma_f32_16x16x32_bf16(Ah, B[nt][0], acc[nt], 0, 0, 0);
      acc[nt] = __builtin_amdgcn_mfma_f32_16x16x32_bf16(Ah, B[nt][1], acc[nt], 0, 0, 0);
      acc[nt] = __builtin_amdgcn_mfma_f32_16x16x32_bf16(Am, B[nt][0], acc[nt], 0, 0, 0);
      acc[nt] = __builtin_amdgcn_mfma_f32_16x16x32_bf16(Am, B[nt][1], acc[nt], 0, 0, 0);
      acc[nt] = __builtin_amdgcn_mfma_f32_16x16x32_bf16(Ah, B[nt][2], acc[nt], 0, 0, 0);
      acc[nt] = __builtin_amdgcn_mfma_f32_16x16x32_bf16(Al, B[nt][0], acc[nt], 0, 0, 0);
    }
    a0 = n0; a1 = n1;
  }

  // combine the 4 K-split partials through LDS (2-way banks = free)
#pragma unroll
  for (int nt = 0; nt < 4; ++nt)
    *(f32x4*)(red + ((wave * 4 + nt) * 64 + lane) * 4) = acc[nt];
  __syncthreads();

  if (wave == 0) {
    f32x4 S[4];
#pragma unroll
    for (int nt = 0; nt < 4; ++nt) {
      S[nt] = acc[nt];
#pragma unroll
      for (int w = 1; w < WSPLIT; ++w)
        S[nt] += *(const f32x4*)(red + ((w * 4 + nt) * 64 + lane) * 4);
    }

    // C layout: token = q*4 + reg, expert = nt*16 + c. 16-lane group per token.
#pragma unroll 1
    for (int r = 0; r < 4; ++r) {
      const int tok = blockIdx.x * 16 + q * 4 + r;
      float v[4] = {S[0][r], S[1][r], S[2][r], S[3][r]};

      float m = fmaxf(fmaxf(v[0], v[1]), fmaxf(v[2], v[3]));
#pragma unroll
      for (int off = 1; off < 16; off <<= 1) m = fmaxf(m, __shfl_xor(m, off));
      float e0 = expf(v[0] - m), e1 = expf(v[1] - m),
            e2 = expf(v[2] - m), e3 = expf(v[3] - m);
      float sd = e0 + e1 + e2 + e3;
#pragma unroll
      for (int off = 1; off < 16; off <<= 1) sd += __shfl_xor(sd, off);
      v[0] = e0 / sd; v[1] = e1 / sd; v[2] = e2 / sd; v[3] = e3 / sd;

      float resv = 0.f; int resi = 0;
#pragma unroll
      for (int rd = 0; rd < TOPK; ++rd) {
        float bv = v[0]; int bi = c;                 // expert id = nt*16 + c
#pragma unroll
        for (int nt = 1; nt < 4; ++nt)
          if (v[nt] > bv) { bv = v[nt]; bi = nt * 16 + c; }  // strict >: low id on tie
#pragma unroll
        for (int off = 1; off < 16; off <<= 1) {
          const float ov = __shfl_xor(bv, off);
          const int   oi = __shfl_xor(bi, off);
          if (ov > bv || (ov == bv && oi < bi)) { bv = ov; bi = oi; }
        }
        if (c == rd) { resv = bv; resi = bi; }
        if ((bi & 15) == c) v[bi >> 4] = -1.f;       // scores > 0, sentinel safe
      }

      if (c < TOPK) {
        out[(size_t)tok * TOPK + c] = (float)resi;
        out[(size_t)TOKENS * TOPK + (size_t)tok * TOPK + c] = resv;
      }
    }
  }
}

extern "C" void kernel_launch(void* const* d_in, const int* in_sizes, int n_in,
                              void* d_out, int out_size, void* d_ws, size_t ws_size,
                              hipStream_t stream) {
  const float* x  = (const float*)d_in[0];
  const float* wg = (const float*)d_in[1];
  float* out = (float*)d_out;
  unsigned short* pw = (unsigned short*)d_ws;   // 786432 B used

  split_w<<<dim3((KDIM * NEXP) / 256), dim3(256), 0, stream>>>(wg, pw);
  gemm_topk<<<dim3(TOKENS / 16), dim3(256), 0, stream>>>(x, pw, out);
}